// Round 1
// baseline (508.214 us; speedup 1.0000x reference)
//
#include <hip/hip_runtime.h>

#define CIN  32
#define COUT 64
#define TT   8
#define HH   56
#define WW   56
#define KK   27
#define SP   (TT * HH * WW)   // 25088 (To*Ho*Wo == T*H*W here: stride1/pad1/dil1)
#define NB   2

// Transpose weight [Cout][Cin][K] -> [K][Cin][Cout] so the hot inner loop
// reads 64 contiguous wave-uniform floats (scalar-load vectorizable).
__global__ __launch_bounds__(256) void transpose_w_kernel(const float* __restrict__ w,
                                                          float* __restrict__ wt) {
    int i = blockIdx.x * 256 + threadIdx.x;
    if (i < COUT * CIN * KK) {
        int co = i / (CIN * KK);
        int r  = i % (CIN * KK);
        int c  = r / KK;
        int k  = r % KK;
        wt[(k * CIN + c) * COUT + co] = w[i];
    }
}

template <bool TRANS>
__global__ __launch_bounds__(256) void dconv3d_kernel(const float* __restrict__ x,
                                                      const float* __restrict__ off,
                                                      const float* __restrict__ w,
                                                      const float* __restrict__ bias,
                                                      float* __restrict__ out) {
    const int s = blockIdx.x * 256 + threadIdx.x;
    if (s >= NB * SP) return;
    const int n  = s / SP;
    const int sp = s % SP;
    const int to = sp / (HH * WW);
    const int hw = sp % (HH * WW);
    const int ho = hw / WW;
    const int wo = hw % WW;

    float acc[COUT];
#pragma unroll
    for (int i = 0; i < COUT; ++i) acc[i] = 0.f;

    const float* xn   = x + (size_t)n * CIN * SP;
    const float* offn = off + (size_t)n * (3 * KK) * SP + sp;

    for (int k = 0; k < KK; ++k) {
        const int kt  = k / 9;
        const int khh = (k / 3) % 3;
        const int kww = k % 3;

        // stride=1, pad=1, dil=1: base = out_coord - 1 + tap
        const float pt = (float)(to - 1 + kt)  + offn[(k * 3 + 0) * SP];
        const float ph = (float)(ho - 1 + khh) + offn[(k * 3 + 1) * SP];
        const float pw = (float)(wo - 1 + kww) + offn[(k * 3 + 2) * SP];

        const float ft = floorf(pt), fh = floorf(ph), fw = floorf(pw);
        const float lt = pt - ft, lh = ph - fh, lw = pw - fw;
        const int t0 = (int)ft, h0 = (int)fh, w0 = (int)fw;

        // Per-axis corner weights with validity folded in (invalid corner -> w=0),
        // indices clamped (matches reference's clip + valid-mask semantics).
        float awt[2], awh[2], aww[2];
        int   it[2], ih[2], iw[2];
        {
            const int t1 = t0 + 1;
            awt[0] = (t0 >= 0 && t0 < TT) ? (1.f - lt) : 0.f;
            awt[1] = (t1 >= 0 && t1 < TT) ? lt : 0.f;
            it[0]  = min(max(t0, 0), TT - 1);
            it[1]  = min(max(t1, 0), TT - 1);
        }
        {
            const int h1 = h0 + 1;
            awh[0] = (h0 >= 0 && h0 < HH) ? (1.f - lh) : 0.f;
            awh[1] = (h1 >= 0 && h1 < HH) ? lh : 0.f;
            ih[0]  = min(max(h0, 0), HH - 1);
            ih[1]  = min(max(h1, 0), HH - 1);
        }
        {
            const int w1 = w0 + 1;
            aww[0] = (w0 >= 0 && w0 < WW) ? (1.f - lw) : 0.f;
            aww[1] = (w1 >= 0 && w1 < WW) ? lw : 0.f;
            iw[0]  = min(max(w0, 0), WW - 1);
            iw[1]  = min(max(w1, 0), WW - 1);
        }

        int   a[8];
        float cw[8];
#pragma unroll
        for (int ci = 0; ci < 8; ++ci) {
            const int i0 = ci >> 2, i1 = (ci >> 1) & 1, i2 = ci & 1;
            a[ci]  = (it[i0] * HH + ih[i1]) * WW + iw[i2];
            cw[ci] = awt[i0] * awh[i1] * aww[i2];
        }

#pragma unroll 2
        for (int c = 0; c < CIN; ++c) {
            const float* xc = xn + c * SP;
            float v = 0.f;
#pragma unroll
            for (int ci = 0; ci < 8; ++ci) v = fmaf(cw[ci], xc[a[ci]], v);

            if (TRANS) {
                const float* wk = w + (k * CIN + c) * COUT;  // wave-uniform, contiguous
#pragma unroll
                for (int co = 0; co < COUT; ++co) acc[co] = fmaf(v, wk[co], acc[co]);
            } else {
#pragma unroll
                for (int co = 0; co < COUT; ++co)
                    acc[co] = fmaf(v, w[(co * CIN + c) * KK + k], acc[co]);
            }
        }
    }

    float* on = out + (size_t)n * COUT * SP + sp;
#pragma unroll
    for (int co = 0; co < COUT; ++co) on[co * SP] = acc[co] + bias[co];
}

extern "C" void kernel_launch(void* const* d_in, const int* in_sizes, int n_in,
                              void* d_out, int out_size, void* d_ws, size_t ws_size,
                              hipStream_t stream) {
    const float* x    = (const float*)d_in[0];
    const float* off  = (const float*)d_in[1];
    const float* w    = (const float*)d_in[2];
    const float* bias = (const float*)d_in[3];
    float* out        = (float*)d_out;

    const int total  = NB * SP;                 // 50176 output positions
    const int blocks = (total + 255) / 256;     // 196

    const size_t wt_bytes = (size_t)COUT * CIN * KK * sizeof(float);  // ~221 KB
    if (ws_size >= wt_bytes) {
        float* wt = (float*)d_ws;
        transpose_w_kernel<<<(COUT * CIN * KK + 255) / 256, 256, 0, stream>>>(w, wt);
        dconv3d_kernel<true><<<blocks, 256, 0, stream>>>(x, off, wt, bias, out);
    } else {
        dconv3d_kernel<false><<<blocks, 256, 0, stream>>>(x, off, w, bias, out);
    }
}